// Round 9
// baseline (246.491 us; speedup 1.0000x reference)
//
#include <hip/hip_runtime.h>

// Problem constants (match reference)
#define ED    32      // embedding / hidden dim
#define SEQ_T 200     // history length
#define NB    4096    // batch
#define H3    96      // 3*ED
#define IV    100001
#define DV    1001
#define DBASE IV            // dept rows start here in xw
#define PBASE (IV + DV)     // price rows (2) start here
#define XWROWS (IV + DV + 2)
#define MASKBIT 0x80000000u
#define IDXMASK 0x7fffffff

typedef __attribute__((ext_vector_type(8))) short bf16x8;   // 8 bf16 (4 VGPRs)
typedef __attribute__((ext_vector_type(4))) float f32x4;    // MFMA acc
typedef __attribute__((ext_vector_type(4))) int   i32x4;

#define LOG2E 1.44269504088896340736f

#if __has_builtin(__builtin_amdgcn_exp2f)
#define EXP2F(x) __builtin_amdgcn_exp2f(x)
#else
#define EXP2F(x) __expf((x) * 0.69314718055994530942f)
#endif

#define MFMA(a, b, c) __builtin_amdgcn_mfma_f32_16x16x32_bf16((a), (b), (c), 0, 0, 0)

__device__ __forceinline__ float rcp_fast(float x) { return __builtin_amdgcn_rcpf(x); }

// round-to-nearest-even fp32 -> bf16 (weights only; one-time cost)
__device__ __forceinline__ short bf16_rn(float v) {
  unsigned u = __float_as_uint(v);
  unsigned r = (u + 0x7fffu + ((u >> 16) & 1u)) >> 16;
  return (short)r;
}
__device__ __forceinline__ float bf16_f(short s) {
  return __uint_as_float(((unsigned)(unsigned short)s) << 16);
}

union I4B8 { i32x4 i; bf16x8 b; };

// Cheap split of 8 fp32 -> (hi, lo) bf16x8 fragments (truncate-hi; exact residual).
__device__ __forceinline__ void split_pack8(const f32x4 c0, const f32x4 c1,
                                            bf16x8& vh, bf16x8& vl) {
  float v[8] = {c0[0], c0[1], c0[2], c0[3], c1[0], c1[1], c1[2], c1[3]};
  float lo[8];
#pragma unroll
  for (int i = 0; i < 8; ++i) {
    const float hif = __uint_as_float(__float_as_uint(v[i]) & 0xffff0000u);
    lo[i] = v[i] - hif;
  }
  I4B8 H, L;
#pragma unroll
  for (int i = 0; i < 4; ++i) {
    H.i[i] = (int)__builtin_amdgcn_perm(__float_as_uint(v[2 * i + 1]),
                                        __float_as_uint(v[2 * i]), 0x07060302u);
    L.i[i] = (int)__builtin_amdgcn_perm(__float_as_uint(lo[2 * i + 1]),
                                        __float_as_uint(lo[2 * i]), 0x07060302u);
  }
  vh = H.b; vl = L.b;
}

// ===========================================================================
// mkidx: per (tower,row,t) combined stream  sidx = xw_row | (update? bit31).
// ===========================================================================
__global__ void __launch_bounds__(256) mkidx(
    const int* __restrict__ ids, const float* __restrict__ prices,
    const int* __restrict__ depts,
    const float* __restrict__ price_mean, const float* __restrict__ price_var,
    int* __restrict__ sidx) {
  const int i = blockIdx.x * 256 + threadIdx.x;
  const int y = blockIdx.y;
  const int total = NB * SEQ_T;
  if (i >= total) return;
  int v;
  if (y == 0) {
    v = ids[i] | (int)MASKBIT;
  } else if (y == 1) {
    const float pn = (prices[i] - price_mean[0]) * rsqrtf(price_var[0]);
    int q = (int)pn;
    q = q < 0 ? 0 : (q > 1 ? 1 : q);
    v = (PBASE + q) | (pn != 0.0f ? (int)MASKBIT : 0);
  } else {
    const int d = depts[i];
    v = (DBASE + d) | (d != 0 ? (int)MASKBIT : 0);
  }
  sidx[y * total + i] = v;
}

// ===========================================================================
// xp_pre_all: xp[v][96] = bias + Wx*e[v] for all three towers (y selects).
// ===========================================================================
__global__ void __launch_bounds__(64) xp_pre_all(
    const float* __restrict__ item_table, const float* __restrict__ dept_table,
    const float* __restrict__ price_table,
    const float* __restrict__ item_Wx, const float* __restrict__ dept_Wx,
    const float* __restrict__ price_Wx,
    const float* __restrict__ item_b, const float* __restrict__ dept_b,
    const float* __restrict__ price_b,
    float* __restrict__ xw) {
  const int y = blockIdx.y;
  const float* emb = (y == 0) ? item_table : (y == 1 ? dept_table : price_table);
  const float* Wx  = (y == 0) ? item_Wx    : (y == 1 ? dept_Wx    : price_Wx);
  const float* Bb  = (y == 0) ? item_b     : (y == 1 ? dept_b     : price_b);
  const int   V    = (y == 0) ? IV : (y == 1 ? DV : 2);
  float* outp = xw + (size_t)((y == 0) ? 0 : (y == 1 ? DBASE : PBASE)) * H3;

  const int r00 = blockIdx.x * 128;
  if (r00 >= V) return;

  const int lane = threadIdx.x & 63;
  const int l15  = lane & 15;
  const int quad = lane >> 4;

  bf16x8 wx_hi[6], wx_lo[6];
#pragma unroll
  for (int tile = 0; tile < 6; ++tile) {
    const float sc = (tile >= 4) ? (2.0f * LOG2E) : LOG2E;
#pragma unroll
    for (int j = 0; j < 8; ++j) {
      const float w = Wx[(quad * 8 + j) * H3 + tile * 16 + l15] * sc;
      const short hi = bf16_rn(w);
      wx_hi[tile][j] = hi;
      wx_lo[tile][j] = bf16_rn(w - bf16_f(hi));
    }
  }
  f32x4 cz[2], cr[2], bi2[2];
#pragma unroll
  for (int tl = 0; tl < 2; ++tl) {
    const int h4 = tl * 16 + quad * 4;
    cz[tl]  = (*(const f32x4*)(Bb + h4)       + *(const f32x4*)(Bb + 96 + h4))  * LOG2E;
    cr[tl]  = (*(const f32x4*)(Bb + 32 + h4)  + *(const f32x4*)(Bb + 128 + h4)) * LOG2E;
    bi2[tl] = *(const f32x4*)(Bb + 64 + h4)  * (2.0f * LOG2E);
  }

  for (int i = 0; i < 8; ++i) {
    const int r0 = r00 + i * 16;
    if (r0 >= V) break;
    int v = r0 + l15;
    if (v > V - 1) v = V - 1;             // clamped lanes dup-write same data
    const f32x4 e0 = *(const f32x4*)(emb + (size_t)v * ED + quad * 8);
    const f32x4 e1 = *(const f32x4*)(emb + (size_t)v * ED + quad * 8 + 4);
    bf16x8 ebh, ebl;
    split_pack8(e0, e1, ebh, ebl);

    float* o = outp + (size_t)v * H3 + quad * 4;
#pragma unroll
    for (int tl = 0; tl < 2; ++tl) {
      f32x4 az = MFMA(wx_hi[tl], ebh, cz[tl]);
      az = MFMA(wx_hi[tl], ebl, az);
      az = MFMA(wx_lo[tl], ebh, az);
      f32x4 ar = MFMA(wx_hi[2 + tl], ebh, cr[tl]);
      ar = MFMA(wx_hi[2 + tl], ebl, ar);
      ar = MFMA(wx_lo[2 + tl], ebh, ar);
      f32x4 ah = MFMA(wx_hi[4 + tl], ebh, bi2[tl]);
      ah = MFMA(wx_hi[4 + tl], ebl, ah);
      ah = MFMA(wx_lo[4 + tl], ebh, ah);
      *(f32x4*)(o + (0 + tl) * 16) = az;
      *(f32x4*)(o + (2 + tl) * 16) = ar;
      *(f32x4*)(o + (4 + tl) * 16) = ah;
    }
  }
}

// ===========================================================================
// gru_uni (round-9): round-8 issue structure + two new levers:
//  * 5-trans fused gate: hn = [h(1+e) + u(1-e)] / [(1+u)(1+e)]
//    (u=2^-az', e=2^-(axh'+r*arh'), r=1/(1+2^-ar')) -- algebraically equal
//    to z*h+(1-z)*tanh(.), one rcp fewer per element (-8 trans/step).
//    Safe: data-scale bounds |az|,|ar| << 30, so u,e never overflow.
//  * depth-2 xp prefetch: gather for t+2 issued at END of step t into the
//    just-freed buffer -> ~1.5 steps (~2000 cy) of latency cover for the
//    HBM-missing part of the xw gather (was ~0.7 step).
// ===========================================================================
__global__ void __launch_bounds__(64, 1) gru_uni(
    const int* __restrict__ sidx, const float* __restrict__ xw,
    const float* __restrict__ item_Wh, const float* __restrict__ item_b,
    const float* __restrict__ price_Wh, const float* __restrict__ price_b,
    const float* __restrict__ dept_Wh, const float* __restrict__ dept_b,
    float* __restrict__ out) {
  const int tower = blockIdx.y;
  const float* Wh = (tower == 0) ? item_Wh : (tower == 1 ? price_Wh : dept_Wh);
  const float* Bb = (tower == 0) ? item_b  : (tower == 1 ? price_b  : dept_b);

  const int lane = threadIdx.x & 63;
  const int l15  = lane & 15;
  const int quad = lane >> 4;
  const int bRow = blockIdx.x * 16 + l15;
  const int rowBase = tower * (NB * SEQ_T) + bRow * SEQ_T;

  // Wh A-fragments k-permuted (hD is directly the B-fragment), pre-scaled.
  bf16x8 wh_hi[6], wh_lo[6];
#pragma unroll
  for (int tile = 0; tile < 6; ++tile) {
    const float sc = (tile >= 4) ? (2.0f * LOG2E) : LOG2E;
#pragma unroll
    for (int j = 0; j < 8; ++j) {
      const int kperm = quad * 4 + (j & 3) + 16 * (j >> 2);
      const float w = Wh[kperm * H3 + tile * 16 + l15] * sc;
      const short hi = bf16_rn(w);
      wh_hi[tile][j] = hi;
      wh_lo[tile][j] = bf16_rn(w - bf16_f(hi));
    }
  }
  f32x4 bh2[2];
#pragma unroll
  for (int tl = 0; tl < 2; ++tl)
    bh2[tl] = *(const f32x4*)(Bb + 160 + tl * 16 + quad * 4) * (2.0f * LOG2E);

  f32x4 hD[2];
  hD[0] = (f32x4)0.0f; hD[1] = (f32x4)0.0f;

  auto reload = [&](i32x4& rv, int t8) {
    const int off = (t8 <= SEQ_T - 4) ? t8 : SEQ_T - 4;   // clamp, stay in-row
    rv = *(const i32x4*)(sidx + rowBase + off);
  };
  auto gatherXp = [&](int sv, f32x4 (&xp)[6]) {
    const float* b = xw + (size_t)(sv & IDXMASK) * H3 + quad * 4;
#pragma unroll
    for (int tile = 0; tile < 6; ++tile)
      xp[tile] = *(const f32x4*)(b + tile * 16);
  };

  // step: consume xpC(t) (mask from csv); at the very end, issue the gather
  // for t+2 (nsv2) into the SAME buffer (freed this step) -> ~1.5-step cover.
  auto stepU = [&](f32x4 (&xpC)[6], int nsv2, int csv) {
    // ---- hh pack first (4 perms): group 1 depends only on this ----
    I4B8 H;
    H.i[0] = (int)__builtin_amdgcn_perm(__float_as_uint(hD[0][1]),
                                        __float_as_uint(hD[0][0]), 0x07060302u);
    H.i[1] = (int)__builtin_amdgcn_perm(__float_as_uint(hD[0][3]),
                                        __float_as_uint(hD[0][2]), 0x07060302u);
    H.i[2] = (int)__builtin_amdgcn_perm(__float_as_uint(hD[1][1]),
                                        __float_as_uint(hD[1][0]), 0x07060302u);
    H.i[3] = (int)__builtin_amdgcn_perm(__float_as_uint(hD[1][3]),
                                        __float_as_uint(hD[1][2]), 0x07060302u);
    const bf16x8 hh = H.b;

    // ---- group 1: wh_hi x hh (6 independent MFMAs) ----
    f32x4 a0 = MFMA(wh_hi[0], hh, xpC[0]);
    f32x4 a1 = MFMA(wh_hi[1], hh, xpC[1]);
    f32x4 a2 = MFMA(wh_hi[2], hh, xpC[2]);
    f32x4 a3 = MFMA(wh_hi[3], hh, xpC[3]);
    f32x4 a4 = MFMA(wh_hi[4], hh, bh2[0]);
    f32x4 a5 = MFMA(wh_hi[5], hh, bh2[1]);

    // ---- hl pack (built while group 1 is in flight) ----
    float lo[8];
#pragma unroll
    for (int tl = 0; tl < 2; ++tl)
#pragma unroll
      for (int rg = 0; rg < 4; ++rg) {
        const float v = hD[tl][rg];
        const float hif = __uint_as_float(__float_as_uint(v) & 0xffff0000u);
        lo[tl * 4 + rg] = v - hif;
      }
    I4B8 L;
#pragma unroll
    for (int i = 0; i < 4; ++i)
      L.i[i] = (int)__builtin_amdgcn_perm(__float_as_uint(lo[2 * i + 1]),
                                          __float_as_uint(lo[2 * i]), 0x07060302u);
    const bf16x8 hl = L.b;

    // ---- group 2: wh_hi x hl ----
    a0 = MFMA(wh_hi[0], hl, a0);
    a1 = MFMA(wh_hi[1], hl, a1);
    a2 = MFMA(wh_hi[2], hl, a2);
    a3 = MFMA(wh_hi[3], hl, a3);
    a4 = MFMA(wh_hi[4], hl, a4);
    a5 = MFMA(wh_hi[5], hl, a5);

    // ---- group 3: wh_lo x hh ----
    a0 = MFMA(wh_lo[0], hh, a0);
    a1 = MFMA(wh_lo[1], hh, a1);
    a2 = MFMA(wh_lo[2], hh, a2);
    a3 = MFMA(wh_lo[3], hh, a3);
    a4 = MFMA(wh_lo[4], hh, a4);
    a5 = MFMA(wh_lo[5], hh, a5);

    // ---- gates pass 1: u, r, and pure-h combos (needs only a0..a3) ----
    float u[8], rr[8], du[8], hpu[8], hmu[8];
#pragma unroll
    for (int tl = 0; tl < 2; ++tl)
#pragma unroll
      for (int rg = 0; rg < 4; ++rg) {
        const int ix = tl * 4 + rg;
        const float az = (tl ? a1 : a0)[rg];
        const float ar = (tl ? a3 : a2)[rg];
        const float w  = EXP2F(-ar);
        u[ix]   = EXP2F(-az);
        rr[ix]  = rcp_fast(1.0f + w);
        du[ix]  = 1.0f + u[ix];
        hpu[ix] = hD[tl][rg] + u[ix];
        hmu[ix] = hD[tl][rg] - u[ix];
      }

    // ---- gates pass 2: h-gate + fused update (needs a4/a5) ----
    const bool mk = (csv < 0);                 // bit31 = update-this-step
#pragma unroll
    for (int tl = 0; tl < 2; ++tl)
#pragma unroll
      for (int rg = 0; rg < 4; ++rg) {
        const int ix = tl * 4 + rg;
        const float arh = (tl ? a5 : a4)[rg];
        const float e   = EXP2F(-__builtin_fmaf(rr[ix], arh, xpC[4 + tl][rg]));
        const float den = du[ix] * (1.0f + e);
        const float num = __builtin_fmaf(e, hmu[ix], hpu[ix]);
        const float hn  = num * rcp_fast(den);
        hD[tl][rg] = mk ? hn : hD[tl][rg];
      }

    // ---- depth-2 prefetch: xp(t+2) into the buffer just consumed ----
    gatherXp(nsv2, xpC);
  };

  // Prologue: sv for steps 0..3 / 4..7; xp(0) and xp(1).
  i32x4 rA = *(const i32x4*)(sidx + rowBase);
  i32x4 rB;
  reload(rB, 4);
  f32x4 xpA[6], xpB[6];
  gatherXp(rA[0], xpA);
  gatherXp(rA[1], xpB);

  for (int t = 0; t < SEQ_T; t += 8) {
    // phase A: steps t..t+3 (A/B alternate; nsv2 = sv(t+2))
    {
      const int s0 = rA[0], s1 = rA[1], s2 = rA[2], s3 = rA[3];
      reload(rA, t + 8);                                  // sv for t+8..t+11
      stepU(xpA, s2, s0);                                 // t   -> fetch t+2
      stepU(xpB, s3, s1);                                 // t+1 -> fetch t+3
      stepU(xpA, rB[0], s2);                              // t+2 -> fetch t+4
      stepU(xpB, rB[1], s3);                              // t+3 -> fetch t+5
    }
    // phase B: steps t+4..t+7
    {
      const int s0 = rB[0], s1 = rB[1], s2 = rB[2], s3 = rB[3];
      reload(rB, t + 12);                                 // sv for t+12..t+15
      stepU(xpA, s2, s0);                                 // t+4 -> fetch t+6
      stepU(xpB, s3, s1);                                 // t+5 -> fetch t+7
      stepU(xpA, rA[0], s2);                              // t+6 -> fetch t+8
      stepU(xpB, rA[1], s3);                              // t+7 -> fetch t+9
    }
  }

#pragma unroll
  for (int tl = 0; tl < 2; ++tl)
    *(f32x4*)(out + (size_t)bRow * H3 + tower * ED + tl * 16 + quad * 4) = hD[tl];
}

// ===========================================================================
// Round-4 verified fallback (used when ws_size is insufficient).
// ===========================================================================
template <int TOWER>
__device__ __forceinline__ void towerR4(
    const int* __restrict__ ids, const float* __restrict__ prices,
    const int* __restrict__ depts, const float* __restrict__ emb,
    const float* __restrict__ Wx, const float* __restrict__ Wh,
    const float* __restrict__ Bb, float pmean, float prsq,
    float* __restrict__ out) {
  const int lane = threadIdx.x & 63;
  const int l15  = lane & 15;
  const int quad = lane >> 4;
  const int bRow = blockIdx.x * 16 + l15;
  const int rowBase = bRow * SEQ_T;

  bf16x8 wh_hi[6], wh_lo[6], wx_hi[6], wx_lo[6];
#pragma unroll
  for (int tile = 0; tile < 6; ++tile) {
    const float sc = (tile >= 4) ? (2.0f * LOG2E) : LOG2E;
#pragma unroll
    for (int j = 0; j < 8; ++j) {
      const int kperm = quad * 4 + (j & 3) + 16 * (j >> 2);
      float w = Wh[kperm * H3 + tile * 16 + l15] * sc;
      short hi = bf16_rn(w);
      wh_hi[tile][j] = hi;
      wh_lo[tile][j] = bf16_rn(w - bf16_f(hi));
      w = Wx[(quad * 8 + j) * H3 + tile * 16 + l15] * sc;
      hi = bf16_rn(w);
      wx_hi[tile][j] = hi;
      wx_lo[tile][j] = bf16_rn(w - bf16_f(hi));
    }
  }

  f32x4 cz[2], cr[2], bi2[2], bh2[2];
#pragma unroll
  for (int tl = 0; tl < 2; ++tl) {
    const int h4 = tl * 16 + quad * 4;
    cz[tl]  = (*(const f32x4*)(Bb + h4)       + *(const f32x4*)(Bb + 96 + h4))  * LOG2E;
    cr[tl]  = (*(const f32x4*)(Bb + 32 + h4)  + *(const f32x4*)(Bb + 128 + h4)) * LOG2E;
    bi2[tl] = *(const f32x4*)(Bb + 64 + h4)  * (2.0f * LOG2E);
    bh2[tl] = *(const f32x4*)(Bb + 160 + h4) * (2.0f * LOG2E);
  }

  f32x4 xz[2][2], xr[2][2], xh[2][2];
  if constexpr (TOWER == 1) {
    bf16x8 f0h, f0l, f1h, f1l;
    split_pack8(*(const f32x4*)(emb + quad * 8),
                *(const f32x4*)(emb + quad * 8 + 4), f0h, f0l);
    split_pack8(*(const f32x4*)(emb + ED + quad * 8),
                *(const f32x4*)(emb + ED + quad * 8 + 4), f1h, f1l);
#pragma unroll
    for (int tl = 0; tl < 2; ++tl) {
      xz[0][tl] = MFMA(wx_hi[tl], f0h, cz[tl]);
      xz[0][tl] = MFMA(wx_hi[tl], f0l, xz[0][tl]);
      xz[0][tl] = MFMA(wx_lo[tl], f0h, xz[0][tl]);
      xz[1][tl] = MFMA(wx_hi[tl], f1h, cz[tl]);
      xz[1][tl] = MFMA(wx_hi[tl], f1l, xz[1][tl]);
      xz[1][tl] = MFMA(wx_lo[tl], f1h, xz[1][tl]);
      xr[0][tl] = MFMA(wx_hi[2 + tl], f0h, cr[tl]);
      xr[0][tl] = MFMA(wx_hi[2 + tl], f0l, xr[0][tl]);
      xr[0][tl] = MFMA(wx_lo[2 + tl], f0h, xr[0][tl]);
      xr[1][tl] = MFMA(wx_hi[2 + tl], f1h, cr[tl]);
      xr[1][tl] = MFMA(wx_hi[2 + tl], f1l, xr[1][tl]);
      xr[1][tl] = MFMA(wx_lo[2 + tl], f1h, xr[1][tl]);
      xh[0][tl] = MFMA(wx_hi[4 + tl], f0h, bi2[tl]);
      xh[0][tl] = MFMA(wx_hi[4 + tl], f0l, xh[0][tl]);
      xh[0][tl] = MFMA(wx_lo[4 + tl], f0h, xh[0][tl]);
      xh[1][tl] = MFMA(wx_hi[4 + tl], f1h, bi2[tl]);
      xh[1][tl] = MFMA(wx_hi[4 + tl], f1l, xh[1][tl]);
      xh[1][tl] = MFMA(wx_lo[4 + tl], f1h, xh[1][tl]);
    }
  }

  f32x4 hD[2];
  hD[0] = (f32x4)0.0f; hD[1] = (f32x4)0.0f;

  const int* sptr = (TOWER == 0) ? ids : (TOWER == 1 ? (const int*)prices : depts);
  f32x4 eA[4][2], eB[4][2];

  auto gather4 = [&](const i32x4& rv, f32x4 (&e)[4][2]) {
#pragma unroll
    for (int j = 0; j < 4; ++j) {
      const float* r = emb + (size_t)rv[j] * ED + quad * 8;
      e[j][0] = *(const f32x4*)r;
      e[j][1] = *(const f32x4*)(r + 4);
    }
  };
  auto reload = [&](i32x4& rv, int t8) {
    const int off = (t8 <= SEQ_T - 4) ? t8 : SEQ_T - 4;
    rv = *(const i32x4*)(sptr + rowBase + off);
  };

  auto gates = [&](f32x4 (&az)[2], f32x4 (&ar)[2], f32x4 (&axh)[2],
                   f32x4 (&arh)[2], bool mk) {
#pragma unroll
    for (int tl = 0; tl < 2; ++tl)
#pragma unroll
      for (int rg = 0; rg < 4; ++rg) {
        const float z  = rcp_fast(1.0f + EXP2F(-az[tl][rg]));
        const float r  = rcp_fast(1.0f + EXP2F(-ar[tl][rg]));
        const float e  = EXP2F(-__builtin_fmaf(r, arh[tl][rg], axh[tl][rg]));
        const float g  = __builtin_fmaf(2.0f, rcp_fast(1.0f + e), -1.0f);
        const float hn = g + z * (hD[tl][rg] - g);
        hD[tl][rg] = (TOWER == 0) ? hn : (mk ? hn : hD[tl][rg]);
      }
  };

  auto step02 = [&](const f32x4 (&ee)[2], int rawid) {
    bf16x8 ebh, ebl, hh, hl;
    split_pack8(ee[0], ee[1], ebh, ebl);
    split_pack8(hD[0], hD[1], hh, hl);
    f32x4 az[2], ar[2], axh[2], arh[2];
#pragma unroll
    for (int tl = 0; tl < 2; ++tl) {
      az[tl]  = MFMA(wx_hi[tl],     ebh, cz[tl]);
      az[tl]  = MFMA(wx_hi[tl],     ebl, az[tl]);
      az[tl]  = MFMA(wx_lo[tl],     ebh, az[tl]);
      az[tl]  = MFMA(wh_hi[tl],     hh,  az[tl]);
      az[tl]  = MFMA(wh_hi[tl],     hl,  az[tl]);
      az[tl]  = MFMA(wh_lo[tl],     hh,  az[tl]);
      ar[tl]  = MFMA(wx_hi[2 + tl], ebh, cr[tl]);
      ar[tl]  = MFMA(wx_hi[2 + tl], ebl, ar[tl]);
      ar[tl]  = MFMA(wx_lo[2 + tl], ebh, ar[tl]);
      ar[tl]  = MFMA(wh_hi[2 + tl], hh,  ar[tl]);
      ar[tl]  = MFMA(wh_hi[2 + tl], hl,  ar[tl]);
      ar[tl]  = MFMA(wh_lo[2 + tl], hh,  ar[tl]);
      axh[tl] = MFMA(wx_hi[4 + tl], ebh, bi2[tl]);
      axh[tl] = MFMA(wx_hi[4 + tl], ebl, axh[tl]);
      axh[tl] = MFMA(wx_lo[4 + tl], ebh, axh[tl]);
      arh[tl] = MFMA(wh_hi[4 + tl], hh,  bh2[tl]);
      arh[tl] = MFMA(wh_hi[4 + tl], hl,  arh[tl]);
      arh[tl] = MFMA(wh_lo[4 + tl], hh,  arh[tl]);
    }
    const bool mk = (TOWER == 2) ? (rawid != 0) : true;
    gates(az, ar, axh, arh, mk);
  };

  auto step1 = [&](int rawbits) {
    const float p  = __int_as_float(rawbits);
    const float pn = (p - pmean) * prsq;
    int q = (int)pn;
    q = q < 0 ? 0 : (q > 1 ? 1 : q);
    const bool one = (q == 1);
    const bool mk  = (pn != 0.0f);
    bf16x8 hh, hl;
    split_pack8(hD[0], hD[1], hh, hl);
    f32x4 az[2], ar[2], axh[2], arh[2];
#pragma unroll
    for (int tl = 0; tl < 2; ++tl) {
#pragma unroll
      for (int i = 0; i < 4; ++i) {
        az[tl][i]  = one ? xz[1][tl][i] : xz[0][tl][i];
        ar[tl][i]  = one ? xr[1][tl][i] : xr[0][tl][i];
        axh[tl][i] = one ? xh[1][tl][i] : xh[0][tl][i];
      }
      az[tl]  = MFMA(wh_hi[tl],     hh, az[tl]);
      az[tl]  = MFMA(wh_hi[tl],     hl, az[tl]);
      az[tl]  = MFMA(wh_lo[tl],     hh, az[tl]);
      ar[tl]  = MFMA(wh_hi[2 + tl], hh, ar[tl]);
      ar[tl]  = MFMA(wh_hi[2 + tl], hl, ar[tl]);
      ar[tl]  = MFMA(wh_lo[2 + tl], hh, ar[tl]);
      arh[tl] = MFMA(wh_hi[4 + tl], hh, bh2[tl]);
      arh[tl] = MFMA(wh_hi[4 + tl], hl, arh[tl]);
      arh[tl] = MFMA(wh_lo[4 + tl], hh, arh[tl]);
    }
    gates(az, ar, axh, arh, mk);
  };

  i32x4 rA = *(const i32x4*)(sptr + rowBase);
  if constexpr (TOWER != 1) gather4(rA, eA);
  i32x4 rB;
  reload(rB, 4);

  for (int t = 0; t < SEQ_T; t += 8) {
    if constexpr (TOWER != 1) gather4(rB, eB);
    {
      const int s0 = rA[0], s1 = rA[1], s2 = rA[2], s3 = rA[3];
      reload(rA, t + 8);
      if constexpr (TOWER == 1) {
        step1(s0); step1(s1); step1(s2); step1(s3);
      } else {
        step02(eA[0], s0); step02(eA[1], s1);
        step02(eA[2], s2); step02(eA[3], s3);
      }
    }
    if constexpr (TOWER != 1) gather4(rA, eA);
    {
      const int s0 = rB[0], s1 = rB[1], s2 = rB[2], s3 = rB[3];
      reload(rB, t + 12);
      if constexpr (TOWER == 1) {
        step1(s0); step1(s1); step1(s2); step1(s3);
      } else {
        step02(eB[0], s0); step02(eB[1], s1);
        step02(eB[2], s2); step02(eB[3], s3);
      }
    }
  }

#pragma unroll
  for (int tl = 0; tl < 2; ++tl)
    *(f32x4*)(out + (size_t)bRow * H3 + TOWER * ED + tl * 16 + quad * 4) = hD[tl];
}

__global__ void __launch_bounds__(64, 1) gru_fb(
    const int* __restrict__ ids, const float* __restrict__ prices, const int* __restrict__ depts,
    const float* __restrict__ item_table, const float* __restrict__ price_table,
    const float* __restrict__ dept_table,
    const float* __restrict__ item_Wx, const float* __restrict__ item_Wh,
    const float* __restrict__ item_b,
    const float* __restrict__ price_Wx, const float* __restrict__ price_Wh,
    const float* __restrict__ price_b,
    const float* __restrict__ dept_Wx, const float* __restrict__ dept_Wh,
    const float* __restrict__ dept_b,
    const float* __restrict__ price_mean, const float* __restrict__ price_var,
    float* __restrict__ out) {
  const int tower = blockIdx.y;
  if (tower == 0) {
    towerR4<0>(ids, prices, depts, item_table, item_Wx, item_Wh, item_b,
               0.0f, 0.0f, out);
  } else if (tower == 1) {
    const float pm = price_mean[0];
    const float pr = rsqrtf(price_var[0]);
    towerR4<1>(ids, prices, depts, price_table, price_Wx, price_Wh, price_b,
               pm, pr, out);
  } else {
    towerR4<2>(ids, prices, depts, dept_table, dept_Wx, dept_Wh, dept_b,
               0.0f, 0.0f, out);
  }
}

extern "C" void kernel_launch(void* const* d_in, const int* in_sizes, int n_in,
                              void* d_out, int out_size, void* d_ws, size_t ws_size,
                              hipStream_t stream) {
  const int*   ids         = (const int*)d_in[0];
  const float* prices      = (const float*)d_in[1];
  const int*   depts       = (const int*)d_in[2];
  const float* item_table  = (const float*)d_in[3];
  const float* price_table = (const float*)d_in[4];
  const float* dept_table  = (const float*)d_in[5];
  const float* item_Wx     = (const float*)d_in[6];
  const float* item_Wh     = (const float*)d_in[7];
  const float* item_b      = (const float*)d_in[8];
  const float* price_Wx    = (const float*)d_in[9];
  const float* price_Wh    = (const float*)d_in[10];
  const float* price_b     = (const float*)d_in[11];
  const float* dept_Wx     = (const float*)d_in[12];
  const float* dept_Wh     = (const float*)d_in[13];
  const float* dept_b      = (const float*)d_in[14];
  const float* price_mean  = (const float*)d_in[15];
  const float* price_var   = (const float*)d_in[16];
  float* out = (float*)d_out;

  const size_t XW_FLOATS = (size_t)XWROWS * H3;
  const size_t SIDX_INTS = (size_t)3 * NB * SEQ_T;
  const size_t NEED = XW_FLOATS * sizeof(float) + SIDX_INTS * sizeof(int);

  dim3 grid(NB / 16, 3, 1);

  if (d_ws != nullptr && ws_size >= NEED) {
    float* xw   = (float*)d_ws;
    int*   sidx = (int*)(xw + XW_FLOATS);
    mkidx<<<dim3((NB * SEQ_T + 255) / 256, 3, 1), 256, 0, stream>>>(
        ids, prices, depts, price_mean, price_var, sidx);
    xp_pre_all<<<dim3((IV + 127) / 128, 3, 1), 64, 0, stream>>>(
        item_table, dept_table, price_table, item_Wx, dept_Wx, price_Wx,
        item_b, dept_b, price_b, xw);
    gru_uni<<<grid, 64, 0, stream>>>(
        sidx, xw, item_Wh, item_b, price_Wh, price_b, dept_Wh, dept_b, out);
  } else {
    gru_fb<<<grid, 64, 0, stream>>>(
        ids, prices, depts, item_table, price_table, dept_table,
        item_Wx, item_Wh, item_b, price_Wx, price_Wh, price_b,
        dept_Wx, dept_Wh, dept_b, price_mean, price_var, out);
  }
}

// Round 10
// 227.055 us; speedup vs baseline: 1.0856x; 1.0856x over previous
//
#include <hip/hip_runtime.h>

// Problem constants (match reference)
#define ED    32      // embedding / hidden dim
#define SEQ_T 200     // history length
#define NB    4096    // batch
#define H3    96      // 3*ED
#define IV    100001
#define DV    1001
#define DBASE IV            // dept rows start here in xw
#define PBASE (IV + DV)     // price rows (2) start here
#define XWROWS (IV + DV + 2)
#define MASKBIT 0x80000000u
#define IDXMASK 0x7fffffff

typedef __attribute__((ext_vector_type(8))) short bf16x8;   // 8 bf16 (4 VGPRs)
typedef __attribute__((ext_vector_type(4))) float f32x4;    // MFMA acc
typedef __attribute__((ext_vector_type(4))) int   i32x4;

#define LOG2E 1.44269504088896340736f

#if __has_builtin(__builtin_amdgcn_exp2f)
#define EXP2F(x) __builtin_amdgcn_exp2f(x)
#else
#define EXP2F(x) __expf((x) * 0.69314718055994530942f)
#endif

#define MFMA(a, b, c) __builtin_amdgcn_mfma_f32_16x16x32_bf16((a), (b), (c), 0, 0, 0)

__device__ __forceinline__ float rcp_fast(float x) { return __builtin_amdgcn_rcpf(x); }

// round-to-nearest-even fp32 -> bf16 (weights only; one-time cost)
__device__ __forceinline__ short bf16_rn(float v) {
  unsigned u = __float_as_uint(v);
  unsigned r = (u + 0x7fffu + ((u >> 16) & 1u)) >> 16;
  return (short)r;
}
__device__ __forceinline__ float bf16_f(short s) {
  return __uint_as_float(((unsigned)(unsigned short)s) << 16);
}

union I4B8 { i32x4 i; bf16x8 b; };

// Cheap split of 8 fp32 -> (hi, lo) bf16x8 fragments (truncate-hi; exact residual).
__device__ __forceinline__ void split_pack8(const f32x4 c0, const f32x4 c1,
                                            bf16x8& vh, bf16x8& vl) {
  float v[8] = {c0[0], c0[1], c0[2], c0[3], c1[0], c1[1], c1[2], c1[3]};
  float lo[8];
#pragma unroll
  for (int i = 0; i < 8; ++i) {
    const float hif = __uint_as_float(__float_as_uint(v[i]) & 0xffff0000u);
    lo[i] = v[i] - hif;
  }
  I4B8 H, L;
#pragma unroll
  for (int i = 0; i < 4; ++i) {
    H.i[i] = (int)__builtin_amdgcn_perm(__float_as_uint(v[2 * i + 1]),
                                        __float_as_uint(v[2 * i]), 0x07060302u);
    L.i[i] = (int)__builtin_amdgcn_perm(__float_as_uint(lo[2 * i + 1]),
                                        __float_as_uint(lo[2 * i]), 0x07060302u);
  }
  vh = H.b; vl = L.b;
}

// ===========================================================================
// mkidx: per (tower,row,t) combined stream  sidx = xw_row | (update? bit31).
// ===========================================================================
__global__ void __launch_bounds__(256) mkidx(
    const int* __restrict__ ids, const float* __restrict__ prices,
    const int* __restrict__ depts,
    const float* __restrict__ price_mean, const float* __restrict__ price_var,
    int* __restrict__ sidx) {
  const int i = blockIdx.x * 256 + threadIdx.x;
  const int y = blockIdx.y;
  const int total = NB * SEQ_T;
  if (i >= total) return;
  int v;
  if (y == 0) {
    v = ids[i] | (int)MASKBIT;
  } else if (y == 1) {
    const float pn = (prices[i] - price_mean[0]) * rsqrtf(price_var[0]);
    int q = (int)pn;
    q = q < 0 ? 0 : (q > 1 ? 1 : q);
    v = (PBASE + q) | (pn != 0.0f ? (int)MASKBIT : 0);
  } else {
    const int d = depts[i];
    v = (DBASE + d) | (d != 0 ? (int)MASKBIT : 0);
  }
  sidx[y * total + i] = v;
}

// ===========================================================================
// xp_pre_all: xp[v][96] = bias + Wx*e[v] for all three towers (y selects).
// ===========================================================================
__global__ void __launch_bounds__(64) xp_pre_all(
    const float* __restrict__ item_table, const float* __restrict__ dept_table,
    const float* __restrict__ price_table,
    const float* __restrict__ item_Wx, const float* __restrict__ dept_Wx,
    const float* __restrict__ price_Wx,
    const float* __restrict__ item_b, const float* __restrict__ dept_b,
    const float* __restrict__ price_b,
    float* __restrict__ xw) {
  const int y = blockIdx.y;
  const float* emb = (y == 0) ? item_table : (y == 1 ? dept_table : price_table);
  const float* Wx  = (y == 0) ? item_Wx    : (y == 1 ? dept_Wx    : price_Wx);
  const float* Bb  = (y == 0) ? item_b     : (y == 1 ? dept_b     : price_b);
  const int   V    = (y == 0) ? IV : (y == 1 ? DV : 2);
  float* outp = xw + (size_t)((y == 0) ? 0 : (y == 1 ? DBASE : PBASE)) * H3;

  const int r00 = blockIdx.x * 128;
  if (r00 >= V) return;

  const int lane = threadIdx.x & 63;
  const int l15  = lane & 15;
  const int quad = lane >> 4;

  bf16x8 wx_hi[6], wx_lo[6];
#pragma unroll
  for (int tile = 0; tile < 6; ++tile) {
    const float sc = (tile >= 4) ? (2.0f * LOG2E) : LOG2E;
#pragma unroll
    for (int j = 0; j < 8; ++j) {
      const float w = Wx[(quad * 8 + j) * H3 + tile * 16 + l15] * sc;
      const short hi = bf16_rn(w);
      wx_hi[tile][j] = hi;
      wx_lo[tile][j] = bf16_rn(w - bf16_f(hi));
    }
  }
  f32x4 cz[2], cr[2], bi2[2];
#pragma unroll
  for (int tl = 0; tl < 2; ++tl) {
    const int h4 = tl * 16 + quad * 4;
    cz[tl]  = (*(const f32x4*)(Bb + h4)       + *(const f32x4*)(Bb + 96 + h4))  * LOG2E;
    cr[tl]  = (*(const f32x4*)(Bb + 32 + h4)  + *(const f32x4*)(Bb + 128 + h4)) * LOG2E;
    bi2[tl] = *(const f32x4*)(Bb + 64 + h4)  * (2.0f * LOG2E);
  }

  for (int i = 0; i < 8; ++i) {
    const int r0 = r00 + i * 16;
    if (r0 >= V) break;
    int v = r0 + l15;
    if (v > V - 1) v = V - 1;             // clamped lanes dup-write same data
    const f32x4 e0 = *(const f32x4*)(emb + (size_t)v * ED + quad * 8);
    const f32x4 e1 = *(const f32x4*)(emb + (size_t)v * ED + quad * 8 + 4);
    bf16x8 ebh, ebl;
    split_pack8(e0, e1, ebh, ebl);

    float* o = outp + (size_t)v * H3 + quad * 4;
#pragma unroll
    for (int tl = 0; tl < 2; ++tl) {
      f32x4 az = MFMA(wx_hi[tl], ebh, cz[tl]);
      az = MFMA(wx_hi[tl], ebl, az);
      az = MFMA(wx_lo[tl], ebh, az);
      f32x4 ar = MFMA(wx_hi[2 + tl], ebh, cr[tl]);
      ar = MFMA(wx_hi[2 + tl], ebl, ar);
      ar = MFMA(wx_lo[2 + tl], ebh, ar);
      f32x4 ah = MFMA(wx_hi[4 + tl], ebh, bi2[tl]);
      ah = MFMA(wx_hi[4 + tl], ebl, ah);
      ah = MFMA(wx_lo[4 + tl], ebh, ah);
      *(f32x4*)(o + (0 + tl) * 16) = az;
      *(f32x4*)(o + (2 + tl) * 16) = ar;
      *(f32x4*)(o + (4 + tl) * 16) = ah;
    }
  }
}

// ===========================================================================
// gru_uni (round-10): EXACT round-8 step body (verified 121.6 us; gates,
// MFMA grouping, mid-step gather placement all identical) with ONE change:
// depth-2 xp prefetch via 4-buffer rotation. Step t consumes x[t&3]; the
// gather for sv(t+2) is issued MID-STEP (between MFMA groups 2 and 3, same
// slot round 8 used) into x[(t+2)&3], which was freed two steps ago (no WAR
// with the gate reads). Every gather has ~1.5 steps (~2200 cy) of flight
// before its consuming MFMA, and any conservative vmcnt drain only meets
// gathers that already have >= 1 full step in flight. Numerics bit-identical
// to rounds 4-8.
// ===========================================================================
__global__ void __launch_bounds__(64, 1) gru_uni(
    const int* __restrict__ sidx, const float* __restrict__ xw,
    const float* __restrict__ item_Wh, const float* __restrict__ item_b,
    const float* __restrict__ price_Wh, const float* __restrict__ price_b,
    const float* __restrict__ dept_Wh, const float* __restrict__ dept_b,
    float* __restrict__ out) {
  const int tower = blockIdx.y;
  const float* Wh = (tower == 0) ? item_Wh : (tower == 1 ? price_Wh : dept_Wh);
  const float* Bb = (tower == 0) ? item_b  : (tower == 1 ? price_b  : dept_b);

  const int lane = threadIdx.x & 63;
  const int l15  = lane & 15;
  const int quad = lane >> 4;
  const int bRow = blockIdx.x * 16 + l15;
  const int rowBase = tower * (NB * SEQ_T) + bRow * SEQ_T;

  // Wh A-fragments k-permuted (hD is directly the B-fragment), pre-scaled.
  bf16x8 wh_hi[6], wh_lo[6];
#pragma unroll
  for (int tile = 0; tile < 6; ++tile) {
    const float sc = (tile >= 4) ? (2.0f * LOG2E) : LOG2E;
#pragma unroll
    for (int j = 0; j < 8; ++j) {
      const int kperm = quad * 4 + (j & 3) + 16 * (j >> 2);
      const float w = Wh[kperm * H3 + tile * 16 + l15] * sc;
      const short hi = bf16_rn(w);
      wh_hi[tile][j] = hi;
      wh_lo[tile][j] = bf16_rn(w - bf16_f(hi));
    }
  }
  f32x4 bh2[2];
#pragma unroll
  for (int tl = 0; tl < 2; ++tl)
    bh2[tl] = *(const f32x4*)(Bb + 160 + tl * 16 + quad * 4) * (2.0f * LOG2E);

  f32x4 hD[2];
  hD[0] = (f32x4)0.0f; hD[1] = (f32x4)0.0f;

  auto reload = [&](i32x4& rv, int t8) {
    const int off = (t8 <= SEQ_T - 4) ? t8 : SEQ_T - 4;   // clamp, stay in-row
    rv = *(const i32x4*)(sidx + rowBase + off);
  };
  auto gatherXp = [&](int sv, f32x4 (&xp)[6]) {
    const float* b = xw + (size_t)(sv & IDXMASK) * H3 + quad * 4;
#pragma unroll
    for (int tile = 0; tile < 6; ++tile)
      xp[tile] = *(const f32x4*)(b + tile * 16);
  };

  // step: consume xpC(t) (mask from csv); mid-step, issue the gather for
  // sv(t+2) into xpP (the buffer freed at step t-2).
  auto stepU = [&](f32x4 (&xpC)[6], f32x4 (&xpP)[6], int nsv2, int csv) {
    // ---- hh pack first (4 perms): group 1 depends only on this ----
    I4B8 H;
    H.i[0] = (int)__builtin_amdgcn_perm(__float_as_uint(hD[0][1]),
                                        __float_as_uint(hD[0][0]), 0x07060302u);
    H.i[1] = (int)__builtin_amdgcn_perm(__float_as_uint(hD[0][3]),
                                        __float_as_uint(hD[0][2]), 0x07060302u);
    H.i[2] = (int)__builtin_amdgcn_perm(__float_as_uint(hD[1][1]),
                                        __float_as_uint(hD[1][0]), 0x07060302u);
    H.i[3] = (int)__builtin_amdgcn_perm(__float_as_uint(hD[1][3]),
                                        __float_as_uint(hD[1][2]), 0x07060302u);
    const bf16x8 hh = H.b;

    // ---- group 1: wh_hi x hh (6 independent MFMAs) ----
    f32x4 a0 = MFMA(wh_hi[0], hh, xpC[0]);
    f32x4 a1 = MFMA(wh_hi[1], hh, xpC[1]);
    f32x4 a2 = MFMA(wh_hi[2], hh, xpC[2]);
    f32x4 a3 = MFMA(wh_hi[3], hh, xpC[3]);
    f32x4 a4 = MFMA(wh_hi[4], hh, bh2[0]);
    f32x4 a5 = MFMA(wh_hi[5], hh, bh2[1]);

    // ---- hl pack (built while group 1 is in flight) ----
    float lo[8];
#pragma unroll
    for (int tl = 0; tl < 2; ++tl)
#pragma unroll
      for (int rg = 0; rg < 4; ++rg) {
        const float v = hD[tl][rg];
        const float hif = __uint_as_float(__float_as_uint(v) & 0xffff0000u);
        lo[tl * 4 + rg] = v - hif;
      }
    I4B8 L;
#pragma unroll
    for (int i = 0; i < 4; ++i)
      L.i[i] = (int)__builtin_amdgcn_perm(__float_as_uint(lo[2 * i + 1]),
                                          __float_as_uint(lo[2 * i]), 0x07060302u);
    const bf16x8 hl = L.b;

    // ---- group 2: wh_hi x hl ----
    a0 = MFMA(wh_hi[0], hl, a0);
    a1 = MFMA(wh_hi[1], hl, a1);
    a2 = MFMA(wh_hi[2], hl, a2);
    a3 = MFMA(wh_hi[3], hl, a3);
    a4 = MFMA(wh_hi[4], hl, a4);
    a5 = MFMA(wh_hi[5], hl, a5);

    // ---- depth-2 xp gather (same mid-step slot as round 8) ----
    gatherXp(nsv2, xpP);

    // ---- group 3: wh_lo x hh ----
    a0 = MFMA(wh_lo[0], hh, a0);
    a1 = MFMA(wh_lo[1], hh, a1);
    a2 = MFMA(wh_lo[2], hh, a2);
    a3 = MFMA(wh_lo[3], hh, a3);
    a4 = MFMA(wh_lo[4], hh, a4);
    a5 = MFMA(wh_lo[5], hh, a5);

    // ---- gates stage 1: z, r (32 trans; overlap in-flight arh MFMAs) ----
    float zv[8], rv[8];
#pragma unroll
    for (int tl = 0; tl < 2; ++tl)
#pragma unroll
      for (int rg = 0; rg < 4; ++rg) {
        const int ix = tl * 4 + rg;
        const float az = (tl ? a1 : a0)[rg];
        const float ar = (tl ? a3 : a2)[rg];
        zv[ix] = rcp_fast(1.0f + EXP2F(-az));
        rv[ix] = rcp_fast(1.0f + EXP2F(-ar));
      }

    // ---- gates stage 2: h-gate + update (needs arh = a4/a5) ----
    const bool mk = (csv < 0);                 // bit31 = update-this-step
#pragma unroll
    for (int tl = 0; tl < 2; ++tl)
#pragma unroll
      for (int rg = 0; rg < 4; ++rg) {
        const int ix = tl * 4 + rg;
        const float arh = (tl ? a5 : a4)[rg];
        const float e  = EXP2F(-__builtin_fmaf(rv[ix], arh, xpC[4 + tl][rg]));
        const float g  = __builtin_fmaf(2.0f, rcp_fast(1.0f + e), -1.0f);
        const float hn = g + zv[ix] * (hD[tl][rg] - g);   // = z*h + (1-z)*g
        hD[tl][rg] = mk ? hn : hD[tl][rg];
      }
  };

  // Prologue: sv for steps 0..3 / 4..7; xp(0) into x0, xp(1) into x1.
  i32x4 rA = *(const i32x4*)(sidx + rowBase);
  i32x4 rB;
  reload(rB, 4);
  f32x4 x0[6], x1[6], x2[6], x3[6];
  gatherXp(rA[0], x0);
  gatherXp(rA[1], x1);

  for (int t = 0; t < SEQ_T; t += 8) {
    // phase A: steps t..t+3; mid-step gathers fetch sv(t+2..t+5)
    {
      const int s0 = rA[0], s1 = rA[1], s2 = rA[2], s3 = rA[3];
      reload(rA, t + 8);                                  // sv for t+8..t+11
      stepU(x0, x2, s2, s0);                              // t   -> fetch t+2
      stepU(x1, x3, s3, s1);                              // t+1 -> fetch t+3
      stepU(x2, x0, rB[0], s2);                           // t+2 -> fetch t+4
      stepU(x3, x1, rB[1], s3);                           // t+3 -> fetch t+5
    }
    // phase B: steps t+4..t+7; gathers fetch sv(t+6..t+9)
    {
      const int u0 = rB[0], u1 = rB[1], u2 = rB[2], u3 = rB[3];
      reload(rB, t + 12);                                 // sv for t+12..t+15
      stepU(x0, x2, u2, u0);                              // t+4 -> fetch t+6
      stepU(x1, x3, u3, u1);                              // t+5 -> fetch t+7
      stepU(x2, x0, rA[0], u2);                           // t+6 -> fetch t+8
      stepU(x3, x1, rA[1], u3);                           // t+7 -> fetch t+9
    }
  }

#pragma unroll
  for (int tl = 0; tl < 2; ++tl)
    *(f32x4*)(out + (size_t)bRow * H3 + tower * ED + tl * 16 + quad * 4) = hD[tl];
}

// ===========================================================================
// Round-4 verified fallback (used when ws_size is insufficient).
// ===========================================================================
template <int TOWER>
__device__ __forceinline__ void towerR4(
    const int* __restrict__ ids, const float* __restrict__ prices,
    const int* __restrict__ depts, const float* __restrict__ emb,
    const float* __restrict__ Wx, const float* __restrict__ Wh,
    const float* __restrict__ Bb, float pmean, float prsq,
    float* __restrict__ out) {
  const int lane = threadIdx.x & 63;
  const int l15  = lane & 15;
  const int quad = lane >> 4;
  const int bRow = blockIdx.x * 16 + l15;
  const int rowBase = bRow * SEQ_T;

  bf16x8 wh_hi[6], wh_lo[6], wx_hi[6], wx_lo[6];
#pragma unroll
  for (int tile = 0; tile < 6; ++tile) {
    const float sc = (tile >= 4) ? (2.0f * LOG2E) : LOG2E;
#pragma unroll
    for (int j = 0; j < 8; ++j) {
      const int kperm = quad * 4 + (j & 3) + 16 * (j >> 2);
      float w = Wh[kperm * H3 + tile * 16 + l15] * sc;
      short hi = bf16_rn(w);
      wh_hi[tile][j] = hi;
      wh_lo[tile][j] = bf16_rn(w - bf16_f(hi));
      w = Wx[(quad * 8 + j) * H3 + tile * 16 + l15] * sc;
      hi = bf16_rn(w);
      wx_hi[tile][j] = hi;
      wx_lo[tile][j] = bf16_rn(w - bf16_f(hi));
    }
  }

  f32x4 cz[2], cr[2], bi2[2], bh2[2];
#pragma unroll
  for (int tl = 0; tl < 2; ++tl) {
    const int h4 = tl * 16 + quad * 4;
    cz[tl]  = (*(const f32x4*)(Bb + h4)       + *(const f32x4*)(Bb + 96 + h4))  * LOG2E;
    cr[tl]  = (*(const f32x4*)(Bb + 32 + h4)  + *(const f32x4*)(Bb + 128 + h4)) * LOG2E;
    bi2[tl] = *(const f32x4*)(Bb + 64 + h4)  * (2.0f * LOG2E);
    bh2[tl] = *(const f32x4*)(Bb + 160 + h4) * (2.0f * LOG2E);
  }

  f32x4 xz[2][2], xr[2][2], xh[2][2];
  if constexpr (TOWER == 1) {
    bf16x8 f0h, f0l, f1h, f1l;
    split_pack8(*(const f32x4*)(emb + quad * 8),
                *(const f32x4*)(emb + quad * 8 + 4), f0h, f0l);
    split_pack8(*(const f32x4*)(emb + ED + quad * 8),
                *(const f32x4*)(emb + ED + quad * 8 + 4), f1h, f1l);
#pragma unroll
    for (int tl = 0; tl < 2; ++tl) {
      xz[0][tl] = MFMA(wx_hi[tl], f0h, cz[tl]);
      xz[0][tl] = MFMA(wx_hi[tl], f0l, xz[0][tl]);
      xz[0][tl] = MFMA(wx_lo[tl], f0h, xz[0][tl]);
      xz[1][tl] = MFMA(wx_hi[tl], f1h, cz[tl]);
      xz[1][tl] = MFMA(wx_hi[tl], f1l, xz[1][tl]);
      xz[1][tl] = MFMA(wx_lo[tl], f1h, xz[1][tl]);
      xr[0][tl] = MFMA(wx_hi[2 + tl], f0h, cr[tl]);
      xr[0][tl] = MFMA(wx_hi[2 + tl], f0l, xr[0][tl]);
      xr[0][tl] = MFMA(wx_lo[2 + tl], f0h, xr[0][tl]);
      xr[1][tl] = MFMA(wx_hi[2 + tl], f1h, cr[tl]);
      xr[1][tl] = MFMA(wx_hi[2 + tl], f1l, xr[1][tl]);
      xr[1][tl] = MFMA(wx_lo[2 + tl], f1h, xr[1][tl]);
      xh[0][tl] = MFMA(wx_hi[4 + tl], f0h, bi2[tl]);
      xh[0][tl] = MFMA(wx_hi[4 + tl], f0l, xh[0][tl]);
      xh[0][tl] = MFMA(wx_lo[4 + tl], f0h, xh[0][tl]);
      xh[1][tl] = MFMA(wx_hi[4 + tl], f1h, bi2[tl]);
      xh[1][tl] = MFMA(wx_hi[4 + tl], f1l, xh[1][tl]);
      xh[1][tl] = MFMA(wx_lo[4 + tl], f1h, xh[1][tl]);
    }
  }

  f32x4 hD[2];
  hD[0] = (f32x4)0.0f; hD[1] = (f32x4)0.0f;

  const int* sptr = (TOWER == 0) ? ids : (TOWER == 1 ? (const int*)prices : depts);
  f32x4 eA[4][2], eB[4][2];

  auto gather4 = [&](const i32x4& rv, f32x4 (&e)[4][2]) {
#pragma unroll
    for (int j = 0; j < 4; ++j) {
      const float* r = emb + (size_t)rv[j] * ED + quad * 8;
      e[j][0] = *(const f32x4*)r;
      e[j][1] = *(const f32x4*)(r + 4);
    }
  };
  auto reload = [&](i32x4& rv, int t8) {
    const int off = (t8 <= SEQ_T - 4) ? t8 : SEQ_T - 4;
    rv = *(const i32x4*)(sptr + rowBase + off);
  };

  auto gates = [&](f32x4 (&az)[2], f32x4 (&ar)[2], f32x4 (&axh)[2],
                   f32x4 (&arh)[2], bool mk) {
#pragma unroll
    for (int tl = 0; tl < 2; ++tl)
#pragma unroll
      for (int rg = 0; rg < 4; ++rg) {
        const float z  = rcp_fast(1.0f + EXP2F(-az[tl][rg]));
        const float r  = rcp_fast(1.0f + EXP2F(-ar[tl][rg]));
        const float e  = EXP2F(-__builtin_fmaf(r, arh[tl][rg], axh[tl][rg]));
        const float g  = __builtin_fmaf(2.0f, rcp_fast(1.0f + e), -1.0f);
        const float hn = g + z * (hD[tl][rg] - g);
        hD[tl][rg] = (TOWER == 0) ? hn : (mk ? hn : hD[tl][rg]);
      }
  };

  auto step02 = [&](const f32x4 (&ee)[2], int rawid) {
    bf16x8 ebh, ebl, hh, hl;
    split_pack8(ee[0], ee[1], ebh, ebl);
    split_pack8(hD[0], hD[1], hh, hl);
    f32x4 az[2], ar[2], axh[2], arh[2];
#pragma unroll
    for (int tl = 0; tl < 2; ++tl) {
      az[tl]  = MFMA(wx_hi[tl],     ebh, cz[tl]);
      az[tl]  = MFMA(wx_hi[tl],     ebl, az[tl]);
      az[tl]  = MFMA(wx_lo[tl],     ebh, az[tl]);
      az[tl]  = MFMA(wh_hi[tl],     hh,  az[tl]);
      az[tl]  = MFMA(wh_hi[tl],     hl,  az[tl]);
      az[tl]  = MFMA(wh_lo[tl],     hh,  az[tl]);
      ar[tl]  = MFMA(wx_hi[2 + tl], ebh, cr[tl]);
      ar[tl]  = MFMA(wx_hi[2 + tl], ebl, ar[tl]);
      ar[tl]  = MFMA(wx_lo[2 + tl], ebh, ar[tl]);
      ar[tl]  = MFMA(wh_hi[2 + tl], hh,  ar[tl]);
      ar[tl]  = MFMA(wh_hi[2 + tl], hl,  ar[tl]);
      ar[tl]  = MFMA(wh_lo[2 + tl], hh,  ar[tl]);
      axh[tl] = MFMA(wx_hi[4 + tl], ebh, bi2[tl]);
      axh[tl] = MFMA(wx_hi[4 + tl], ebl, axh[tl]);
      axh[tl] = MFMA(wx_lo[4 + tl], ebh, axh[tl]);
      arh[tl] = MFMA(wh_hi[4 + tl], hh,  bh2[tl]);
      arh[tl] = MFMA(wh_hi[4 + tl], hl,  arh[tl]);
      arh[tl] = MFMA(wh_lo[4 + tl], hh,  arh[tl]);
    }
    const bool mk = (TOWER == 2) ? (rawid != 0) : true;
    gates(az, ar, axh, arh, mk);
  };

  auto step1 = [&](int rawbits) {
    const float p  = __int_as_float(rawbits);
    const float pn = (p - pmean) * prsq;
    int q = (int)pn;
    q = q < 0 ? 0 : (q > 1 ? 1 : q);
    const bool one = (q == 1);
    const bool mk  = (pn != 0.0f);
    bf16x8 hh, hl;
    split_pack8(hD[0], hD[1], hh, hl);
    f32x4 az[2], ar[2], axh[2], arh[2];
#pragma unroll
    for (int tl = 0; tl < 2; ++tl) {
#pragma unroll
      for (int i = 0; i < 4; ++i) {
        az[tl][i]  = one ? xz[1][tl][i] : xz[0][tl][i];
        ar[tl][i]  = one ? xr[1][tl][i] : xr[0][tl][i];
        axh[tl][i] = one ? xh[1][tl][i] : xh[0][tl][i];
      }
      az[tl]  = MFMA(wh_hi[tl],     hh, az[tl]);
      az[tl]  = MFMA(wh_hi[tl],     hl, az[tl]);
      az[tl]  = MFMA(wh_lo[tl],     hh, az[tl]);
      ar[tl]  = MFMA(wh_hi[2 + tl], hh, ar[tl]);
      ar[tl]  = MFMA(wh_hi[2 + tl], hl, ar[tl]);
      ar[tl]  = MFMA(wh_lo[2 + tl], hh, ar[tl]);
      arh[tl] = MFMA(wh_hi[4 + tl], hh, bh2[tl]);
      arh[tl] = MFMA(wh_hi[4 + tl], hl, arh[tl]);
      arh[tl] = MFMA(wh_lo[4 + tl], hh, arh[tl]);
    }
    gates(az, ar, axh, arh, mk);
  };

  i32x4 rA = *(const i32x4*)(sptr + rowBase);
  if constexpr (TOWER != 1) gather4(rA, eA);
  i32x4 rB;
  reload(rB, 4);

  for (int t = 0; t < SEQ_T; t += 8) {
    if constexpr (TOWER != 1) gather4(rB, eB);
    {
      const int s0 = rA[0], s1 = rA[1], s2 = rA[2], s3 = rA[3];
      reload(rA, t + 8);
      if constexpr (TOWER == 1) {
        step1(s0); step1(s1); step1(s2); step1(s3);
      } else {
        step02(eA[0], s0); step02(eA[1], s1);
        step02(eA[2], s2); step02(eA[3], s3);
      }
    }
    if constexpr (TOWER != 1) gather4(rA, eA);
    {
      const int s0 = rB[0], s1 = rB[1], s2 = rB[2], s3 = rB[3];
      reload(rB, t + 12);
      if constexpr (TOWER == 1) {
        step1(s0); step1(s1); step1(s2); step1(s3);
      } else {
        step02(eB[0], s0); step02(eB[1], s1);
        step02(eB[2], s2); step02(eB[3], s3);
      }
    }
  }

#pragma unroll
  for (int tl = 0; tl < 2; ++tl)
    *(f32x4*)(out + (size_t)bRow * H3 + TOWER * ED + tl * 16 + quad * 4) = hD[tl];
}

__global__ void __launch_bounds__(64, 1) gru_fb(
    const int* __restrict__ ids, const float* __restrict__ prices, const int* __restrict__ depts,
    const float* __restrict__ item_table, const float* __restrict__ price_table,
    const float* __restrict__ dept_table,
    const float* __restrict__ item_Wx, const float* __restrict__ item_Wh,
    const float* __restrict__ item_b,
    const float* __restrict__ price_Wx, const float* __restrict__ price_Wh,
    const float* __restrict__ price_b,
    const float* __restrict__ dept_Wx, const float* __restrict__ dept_Wh,
    const float* __restrict__ dept_b,
    const float* __restrict__ price_mean, const float* __restrict__ price_var,
    float* __restrict__ out) {
  const int tower = blockIdx.y;
  if (tower == 0) {
    towerR4<0>(ids, prices, depts, item_table, item_Wx, item_Wh, item_b,
               0.0f, 0.0f, out);
  } else if (tower == 1) {
    const float pm = price_mean[0];
    const float pr = rsqrtf(price_var[0]);
    towerR4<1>(ids, prices, depts, price_table, price_Wx, price_Wh, price_b,
               pm, pr, out);
  } else {
    towerR4<2>(ids, prices, depts, dept_table, dept_Wx, dept_Wh, dept_b,
               0.0f, 0.0f, out);
  }
}

extern "C" void kernel_launch(void* const* d_in, const int* in_sizes, int n_in,
                              void* d_out, int out_size, void* d_ws, size_t ws_size,
                              hipStream_t stream) {
  const int*   ids         = (const int*)d_in[0];
  const float* prices      = (const float*)d_in[1];
  const int*   depts       = (const int*)d_in[2];
  const float* item_table  = (const float*)d_in[3];
  const float* price_table = (const float*)d_in[4];
  const float* dept_table  = (const float*)d_in[5];
  const float* item_Wx     = (const float*)d_in[6];
  const float* item_Wh     = (const float*)d_in[7];
  const float* item_b      = (const float*)d_in[8];
  const float* price_Wx    = (const float*)d_in[9];
  const float* price_Wh    = (const float*)d_in[10];
  const float* price_b     = (const float*)d_in[11];
  const float* dept_Wx     = (const float*)d_in[12];
  const float* dept_Wh     = (const float*)d_in[13];
  const float* dept_b      = (const float*)d_in[14];
  const float* price_mean  = (const float*)d_in[15];
  const float* price_var   = (const float*)d_in[16];
  float* out = (float*)d_out;

  const size_t XW_FLOATS = (size_t)XWROWS * H3;
  const size_t SIDX_INTS = (size_t)3 * NB * SEQ_T;
  const size_t NEED = XW_FLOATS * sizeof(float) + SIDX_INTS * sizeof(int);

  dim3 grid(NB / 16, 3, 1);

  if (d_ws != nullptr && ws_size >= NEED) {
    float* xw   = (float*)d_ws;
    int*   sidx = (int*)(xw + XW_FLOATS);
    mkidx<<<dim3((NB * SEQ_T + 255) / 256, 3, 1), 256, 0, stream>>>(
        ids, prices, depts, price_mean, price_var, sidx);
    xp_pre_all<<<dim3((IV + 127) / 128, 3, 1), 64, 0, stream>>>(
        item_table, dept_table, price_table, item_Wx, dept_Wx, price_Wx,
        item_b, dept_b, price_b, xw);
    gru_uni<<<grid, 64, 0, stream>>>(
        sidx, xw, item_Wh, item_b, price_Wh, price_b, dept_Wh, dept_b, out);
  } else {
    gru_fb<<<grid, 64, 0, stream>>>(
        ids, prices, depts, item_table, price_table, dept_table,
        item_Wx, item_Wh, item_b, price_Wx, price_Wh, price_b,
        dept_Wx, dept_Wh, dept_b, price_mean, price_var, out);
  }
}